// Round 7
// baseline (267.161 us; speedup 1.0000x reference)
//
#include <hip/hip_runtime.h>
#include <hip/hip_bf16.h>

#define BB 4
#define LL 1024
#define CC 768
#define HH 12
#define DD 64

typedef unsigned short ushort_t;
typedef __attribute__((ext_vector_type(8))) short bf16x8;
typedef __attribute__((ext_vector_type(4))) float f32x4;
typedef __attribute__((ext_vector_type(2))) float f32x2;
typedef __attribute__((ext_vector_type(2))) unsigned u32x2;

__device__ inline ushort_t f2bf(float x) {
    union { float f; unsigned u; } v; v.f = x;
    unsigned r = (v.u + 0x7FFFu + ((v.u >> 16) & 1u)) >> 16;
    return (ushort_t)r;
}
__device__ inline float u2f(unsigned u) {
    union { unsigned u; float f; } v; v.u = u;
    return v.f;
}
// pack two f32 -> packed 2xbf16 (RNE) via the HW cvt_pk path
__device__ inline unsigned pack2bf(float lo, float hi) {
    union { __hip_bfloat162 v; unsigned u; } r;
    r.v = __float22bfloat162_rn(make_float2(lo, hi));
    return r.u;
}

// Stage rows x 32 shorts from g (row stride `stride` shorts) into LDS,
// contiguous 64B rows, via async global->LDS (16B/lane, wave-uniform LDS base).
__device__ inline void stage_rows(const ushort_t* __restrict__ g, int stride,
                                  ushort_t* lds, int nbytes, int wave, int lane) {
    const int ko = (lane & 3) << 3;
    const int rsub = lane >> 2;
    for (int off = wave * 1024; off < nbytes; off += 4096) {
        int row = (off >> 6) + rsub;
        __builtin_amdgcn_global_load_lds(
            (const __attribute__((address_space(1))) void*)(g + (size_t)row * stride + ko),
            (__attribute__((address_space(3))) void*)(lds + (off >> 1)),
            16, 0, 0);
    }
}

// ---------------- prep: cast inputs + cast/transpose weights + zero Z (one launch) --------
__global__ __launch_bounds__(256) void prep(const float* __restrict__ q, const float* __restrict__ kv,
                                            const float* __restrict__ w0, const float* __restrict__ w1,
                                            const float* __restrict__ w2, const float* __restrict__ w3,
                                            ushort_t* __restrict__ qo, ushort_t* __restrict__ kvo,
                                            ushort_t* __restrict__ o0, ushort_t* __restrict__ o1,
                                            ushort_t* __restrict__ o2, ushort_t* __restrict__ o3,
                                            float* __restrict__ Zp) {
    __shared__ float t[32][33];
    const int bx = blockIdx.x;
    if (bx < 3072) {
        const float* src = bx < 1536 ? q : kv;
        ushort_t* dst = bx < 1536 ? qo : kvo;
        int bb = bx < 1536 ? bx : bx - 1536;
        size_t i = ((size_t)bb * 256 + threadIdx.x) * 8;
        float4 a = *(const float4*)(src + i);
        float4 b = *(const float4*)(src + i + 4);
        ushort_t u[8] = {f2bf(a.x), f2bf(a.y), f2bf(a.z), f2bf(a.w),
                         f2bf(b.x), f2bf(b.y), f2bf(b.z), f2bf(b.w)};
        *(uint4*)(dst + i) = *(uint4*)u;
    } else if (bx < 5376) {
        int w = bx - 3072;
        int z = w / 576, rem = w % 576;
        const float* W = z == 0 ? w0 : z == 1 ? w1 : z == 2 ? w2 : w3;
        ushort_t* Wt   = z == 0 ? o0 : z == 1 ? o1 : z == 2 ? o2 : o3;
        const int c = threadIdx.x & 31, r0 = threadIdx.x >> 5;
        const int kb = (rem / 24) * 32, nb = (rem % 24) * 32;
#pragma unroll
        for (int i = 0; i < 4; ++i)
            t[r0 + 8 * i][c] = W[(size_t)(kb + r0 + 8 * i) * CC + nb + c];
        __syncthreads();
#pragma unroll
        for (int i = 0; i < 4; ++i)
            Wt[(size_t)(nb + r0 + 8 * i) * CC + kb + c] = f2bf(t[c][r0 + 8 * i]);
    } else {
        // zero softmax denominators: 4*12*1024 floats over 192 blocks
        Zp[(bx - 5376) * 256 + threadIdx.x] = 0.f;
    }
}

// ---------------- fused Q/K/V projection (MFMA bf16), z picks target ----------------
// Q and K are written PRE-TILED in MFMA-fragment order:
//   per (b,h) plane of 64K elems: off = ((l>>4)*8 + (d>>3))*128 + (l&15)*8 + (d&7)
// so qk_premix can load fragments as contiguous 1KB wave-reads with no LDS.
__global__ __launch_bounds__(256) void proj_gemm(const ushort_t* __restrict__ Aq,
                                                 const ushort_t* __restrict__ Akv,
                                                 const ushort_t* __restrict__ Wqt,
                                                 const ushort_t* __restrict__ Wkt,
                                                 const ushort_t* __restrict__ Wvt,
                                                 ushort_t* __restrict__ Qo,
                                                 ushort_t* __restrict__ Ko,
                                                 ushort_t* __restrict__ Vto) {
    const int z = blockIdx.z;
    const ushort_t* A  = (z == 0) ? Aq : Akv;
    const ushort_t* Wt = (z == 0) ? Wqt : (z == 1 ? Wkt : Wvt);

    __shared__ __align__(16) ushort_t a_lds[128 * 32];
    __shared__ __align__(16) ushort_t b_lds[128 * 32];

    const int tid = threadIdx.x;
    const int bm = blockIdx.x * 128, bn = blockIdx.y * 128;
    const int wave = tid >> 6, lane = tid & 63;
    const int quad = lane >> 4, lq = lane & 15;
    const int wr = wave >> 1, wc = wave & 1;

    f32x4 acc[4][4] = {};

    for (int k0 = 0; k0 < CC; k0 += 32) {
        stage_rows(A + (size_t)bm * CC + k0, CC, a_lds, 8192, wave, lane);
        stage_rows(Wt + (size_t)bn * CC + k0, CC, b_lds, 8192, wave, lane);
        __syncthreads();
        bf16x8 af[4], bfr[4];
#pragma unroll
        for (int mi = 0; mi < 4; ++mi)
            af[mi] = *(bf16x8*)&a_lds[(wr * 64 + mi * 16 + lq) * 32 + quad * 8];
#pragma unroll
        for (int ni = 0; ni < 4; ++ni)
            bfr[ni] = *(bf16x8*)&b_lds[(wc * 64 + ni * 16 + lq) * 32 + quad * 8];
#pragma unroll
        for (int mi = 0; mi < 4; ++mi)
#pragma unroll
            for (int ni = 0; ni < 4; ++ni)
                acc[mi][ni] = __builtin_amdgcn_mfma_f32_16x16x32_bf16(af[mi], bfr[ni], acc[mi][ni], 0, 0, 0);
        __syncthreads();
    }

    const float scale = (z == 0) ? 0.125f : 1.0f;
#pragma unroll
    for (int mi = 0; mi < 4; ++mi)
#pragma unroll
        for (int ni = 0; ni < 4; ++ni)
#pragma unroll
            for (int r = 0; r < 4; ++r) {
                int row = bm + wr * 64 + mi * 16 + quad * 4 + r;  // b*1024 + l(or k)
                int col = bn + wc * 64 + ni * 16 + lq;            // h*64 + d
                int b = row >> 10, l = row & 1023, h = col >> 6, d = col & 63;
                ushort_t v = f2bf(acc[mi][ni][r] * scale);
                if (z == 2) {
                    Vto[((size_t)(b * HH + h) * DD + d) * LL + l] = v;
                } else {
                    size_t off = (size_t)(b * HH + h) * (LL * DD)
                               + (size_t)(((l >> 4) * 8 + (d >> 3)) * 128 + (l & 15) * 8 + (d & 7));
                    if (z == 0) Qo[off] = v;
                    else        Ko[off] = v;
                }
            }
}

// ---------------- QK^T fused with premix + exp + denominator accumulation ----------------
// Barrier-free, LDS-free. E stored bf16 in PV-friendly tiled layout:
//   E[b][lt][k][li][h], lt = l>>4, li = l&15  (each pv block's slice is 384KB contiguous)
__global__ __launch_bounds__(256) void qk_premix(const ushort_t* __restrict__ Qf,
                                                 const ushort_t* __restrict__ Kf,
                                                 const float* __restrict__ Wpre,
                                                 ushort_t* __restrict__ E,
                                                 float* __restrict__ Z) {
    const int tid = threadIdx.x;
    const int lane = tid & 63, wave = tid >> 6;
    const int quad = lane >> 4, lq = lane & 15;
    const int wr = wave >> 1, wc = wave & 1;

    // XCD-aware decode: xcd = x%8 (round-robin dispatch); each XCD-pair owns one b.
    const int x = blockIdx.x;
    const int xcd = x & 7;
    const int b = xcd >> 1;                           // 0..3
    const int s = x >> 3;                             // 0..511
    const int bk = (s & 31) << 5;                     // k-tile base
    const int bl = ((((s >> 5) << 1) | (xcd & 1))) << 5;  // l-tile base

    // fragment bases: per (b,h) plane LL*DD elems; k16-block = 1024 elems (2KB)
    const ushort_t* Kp = Kf + (size_t)b * HH * LL * DD
                       + (size_t)(((bk >> 4) + wr) * 1024 + quad * 128 + lq * 8);
    const ushort_t* Qp = Qf + (size_t)b * HH * LL * DD
                       + (size_t)(((bl >> 4) + wc) * 1024 + quad * 128 + lq * 8);

    f32x4 acc[HH] = {};
#pragma unroll
    for (int h = 0; h < HH; ++h) {
        const size_t ho = (size_t)h * (LL * DD);
        bf16x8 ka0 = *(const bf16x8*)(Kp + ho);
        bf16x8 ka1 = *(const bf16x8*)(Kp + ho + 512);
        bf16x8 qb0 = *(const bf16x8*)(Qp + ho);
        bf16x8 qb1 = *(const bf16x8*)(Qp + ho + 512);
        acc[h] = __builtin_amdgcn_mfma_f32_16x16x32_bf16(ka0, qb0, acc[h], 0, 0, 0);
        acc[h] = __builtin_amdgcn_mfma_f32_16x16x32_bf16(ka1, qb1, acc[h], 0, 0, 0);
    }

    // premix (fp32, thread-local across heads) + exp + pack bf16 pairs (heads 2i,2i+1)
    unsigned pk[6][4];
#pragma unroll
    for (int i2 = 0; i2 < 6; ++i2) {
        f32x4 m0 = {}, m1 = {};
#pragma unroll
        for (int h = 0; h < HH; ++h) {
            m0 += acc[h] * Wpre[h * HH + 2 * i2];
            m1 += acc[h] * Wpre[h * HH + 2 * i2 + 1];
        }
#pragma unroll
        for (int r = 0; r < 4; ++r)
            pk[i2][r] = pack2bf(__expf(m0[r]), __expf(m1[r]));
    }

    // denominator partials from ROUNDED values: sum this thread's 4 k-rows,
    // reduce across quads (k groups), atomically add per (i, l).
    float zp[HH];
#pragma unroll
    for (int i2 = 0; i2 < 6; ++i2) {
        float s0 = 0.f, s1 = 0.f;
#pragma unroll
        for (int r = 0; r < 4; ++r) {
            s0 += u2f(pk[i2][r] << 16);
            s1 += u2f(pk[i2][r] & 0xFFFF0000u);
        }
        zp[2 * i2] = s0; zp[2 * i2 + 1] = s1;
    }
#pragma unroll
    for (int i = 0; i < HH; ++i) {
        zp[i] += __shfl_xor(zp[i], 16);
        zp[i] += __shfl_xor(zp[i], 32);
    }
    if (quad == 0) {
#pragma unroll
        for (int i = 0; i < HH; ++i)
            atomicAdd(&Z[((size_t)b * HH + i) * LL + bl + wc * 16 + lq], zp[i]);
    }

    // store E[b][lt][k][li][12], NT (don't evict Q/K from L2)
    const int ltw = (bl >> 4) + wc;   // l-tile index of this thread's column
#pragma unroll
    for (int r = 0; r < 4; ++r) {
        const int k = bk + wr * 16 + quad * 4 + r;
        ushort_t* ep = E + (((size_t)(b * 64 + ltw) * 1024 + k) * 16 + lq) * 12;
        u32x2 s0; s0.x = pk[0][r]; s0.y = pk[1][r];
        u32x2 s1; s1.x = pk[2][r]; s1.y = pk[3][r];
        u32x2 s2; s2.x = pk[4][r]; s2.y = pk[5][r];
        __builtin_nontemporal_store(s0, (u32x2*)ep);
        __builtin_nontemporal_store(s1, (u32x2*)(ep + 4));
        __builtin_nontemporal_store(s2, (u32x2*)(ep + 8));
    }
}

// ---------------- PV fused with normalize + postmix (v5: barrier-free, LDS-free) ----------
// Block = (b, 16 l-rows), 256 threads / 4 waves; wave w owns out-heads {3w,3w+1,3w+2}
// for ALL 64 d. Each thread postmixes exactly the E values its MFMA A-fragment needs
// (P[row=lq][k=quad*8+j]) -> mixed P goes straight into registers. No LDS, no barriers;
// software-pipelined K=32 halves (named eA/eB reg buffers, all statically indexed).
// V fragments direct from global (L2-resident via XCD-pair b pinning).
__global__ __launch_bounds__(256, 1) void pv_postmix(const ushort_t* __restrict__ E,
                                                     const ushort_t* __restrict__ Vt,
                                                     const float* __restrict__ Wpost,
                                                     const float* __restrict__ Z,
                                                     ushort_t* __restrict__ att) {
    const int tid = threadIdx.x;
    const int lane = tid & 63, wave = tid >> 6;
    const int quad = lane >> 4, lq = lane & 15;
    const int hh0 = wave * 3;                  // this wave's first out-head

    // decode: 256 blocks; xcd = bid&7 -> b; lt = 2*(bid>>3) + (xcd&1)
    const int bid = blockIdx.x;
    const int xcd = bid & 7;
    const int b = xcd >> 1;
    const int lt = ((bid >> 3) << 1) | (xcd & 1);
    const int bl = lt << 4;

    // postmix weights for this wave's 3 out-heads
    float wp[HH][3];
#pragma unroll
    for (int h = 0; h < HH; ++h)
#pragma unroll
        for (int ii = 0; ii < 3; ++ii)
            wp[h][ii] = Wpost[h * HH + hh0 + ii];

    // inverse denominators at this thread's P-row (l = bl + lq)
    float invZ[HH];
#pragma unroll
    for (int h = 0; h < HH; ++h)
        invZ[h] = 1.0f / Z[((size_t)b * HH + h) * LL + bl + lq];

    // E base: E[b][lt][k][li][12]; this thread reads k = kt*64+k0*32+quad*8+j, li = lq
    const ushort_t* eslice = E + (size_t)(b * 64 + lt) * (1024 * 192)
                           + (size_t)(quad * 8) * 192 + lq * 12;
    // V base: Vt[(b*12+h)][d][k]; frag lane (quad,lq): d = dq*16+lq, k-chunk quad*8
    const ushort_t* vbase = Vt + ((size_t)(b * HH + hh0) * DD + lq) * LL + quad * 8;

    f32x4 acc[3][4] = {};
    u32x2 eA[24], eB[24];
    bf16x8 vf[12];

#define LOADE(dst, kt_, k0_)                                                              \
    do {                                                                                  \
        const ushort_t* ep_ = eslice + (size_t)((kt_) * 64 + (k0_) * 32) * 192;           \
        _Pragma("unroll")                                                                 \
        for (int j_ = 0; j_ < 8; ++j_)                                                    \
            _Pragma("unroll")                                                             \
            for (int c_ = 0; c_ < 3; ++c_)                                                \
                dst[j_ * 3 + c_] = *(const u32x2*)(ep_ + j_ * 192 + c_ * 4);              \
    } while (0)

#define LOADV(kt_, k0_)                                                                   \
    do {                                                                                  \
        _Pragma("unroll")                                                                 \
        for (int ii_ = 0; ii_ < 3; ++ii_)                                                 \
            _Pragma("unroll")                                                             \
            for (int dq_ = 0; dq_ < 4; ++dq_)                                             \
                vf[ii_ * 4 + dq_] = *(const bf16x8*)(vbase                                \
                    + (size_t)(ii_ * DD + dq_ * 16) * LL + (kt_) * 64 + (k0_) * 32);      \
    } while (0)

    // one K=32 half: postmix 8 positions from src regs -> 3 A-frags -> 12 MFMA
#define HALF(src)                                                                         \
    do {                                                                                  \
        union { bf16x8 v; unsigned d[4]; } pa_[3];                                        \
        _Pragma("unroll")                                                                 \
        for (int j2_ = 0; j2_ < 4; ++j2_) {                                               \
            float p0_[3] = {0.f, 0.f, 0.f}, p1_[3] = {0.f, 0.f, 0.f};                     \
            _Pragma("unroll")                                                             \
            for (int c_ = 0; c_ < 3; ++c_) {                                              \
                u32x2 ea_ = src[(2 * j2_) * 3 + c_];                                      \
                u32x2 eb_ = src[(2 * j2_ + 1) * 3 + c_];                                  \
                float f0_ = u2f(ea_.x << 16)         * invZ[4 * c_ + 0];                  \
                float f1_ = u2f(ea_.x & 0xFFFF0000u) * invZ[4 * c_ + 1];                  \
                float f2_ = u2f(ea_.y << 16)         * invZ[4 * c_ + 2];                  \
                float f3_ = u2f(ea_.y & 0xFFFF0000u) * invZ[4 * c_ + 3];                  \
                float g0_ = u2f(eb_.x << 16)         * invZ[4 * c_ + 0];                  \
                float g1_ = u2f(eb_.x & 0xFFFF0000u) * invZ[4 * c_ + 1];                  \
                float g2_ = u2f(eb_.y << 16)         * invZ[4 * c_ + 2];                  \
                float g3_ = u2f(eb_.y & 0xFFFF0000u) * invZ[4 * c_ + 3];                  \
                _Pragma("unroll")                                                         \
                for (int ii_ = 0; ii_ < 3; ++ii_) {                                       \
                    p0_[ii_] += f0_ * wp[4 * c_ + 0][ii_] + f1_ * wp[4 * c_ + 1][ii_]     \
                              + f2_ * wp[4 * c_ + 2][ii_] + f3_ * wp[4 * c_ + 3][ii_];    \
                    p1_[ii_] += g0_ * wp[4 * c_ + 0][ii_] + g1_ * wp[4 * c_ + 1][ii_]     \
                              + g2_ * wp[4 * c_ + 2][ii_] + g3_ * wp[4 * c_ + 3][ii_];    \
                }                                                                         \
            }                                                                             \
            _Pragma("unroll")                                                             \
            for (int ii_ = 0; ii_ < 3; ++ii_)                                             \
                pa_[ii_].d[j2_] = pack2bf(p0_[ii_], p1_[ii_]);                            \
        }                                                                                 \
        _Pragma("unroll")                                                                 \
        for (int ii_ = 0; ii_ < 3; ++ii_)                                                 \
            _Pragma("unroll")                                                             \
            for (int dq_ = 0; dq_ < 4; ++dq_)                                             \
                acc[ii_][dq_] = __builtin_amdgcn_mfma_f32_16x16x32_bf16(                  \
                    pa_[ii_].v, vf[ii_ * 4 + dq_], acc[ii_][dq_], 0, 0, 0);               \
    } while (0)

    LOADE(eA, 0, 0);
#pragma unroll 1
    for (int kt = 0; kt < 16; ++kt) {
        LOADE(eB, kt, 1);       // prefetch second half of this kt
        LOADV(kt, 0);
        HALF(eA);
        if (kt < 15) LOADE(eA, kt + 1, 0);   // prefetch first half of next kt
        LOADV(kt, 1);
        HALF(eB);
    }
#undef LOADE
#undef LOADV
#undef HALF

#pragma unroll
    for (int ii = 0; ii < 3; ++ii)
#pragma unroll
        for (int dq = 0; dq < 4; ++dq)
#pragma unroll
            for (int r = 0; r < 4; ++r)
                att[((size_t)b * LL + bl + quad * 4 + r) * CC + (hh0 + ii) * 64 + dq * 16 + lq] =
                    f2bf(acc[ii][dq][r]);
}

// ---------------- out = att @ Wout (MFMA, fp32 out). BM=128, BN=64 -> 384 blocks ----------------
__global__ __launch_bounds__(256) void out_gemm(const ushort_t* __restrict__ A,
                                                const ushort_t* __restrict__ Wt,
                                                float* __restrict__ out) {
    __shared__ __align__(16) ushort_t a_lds[128 * 32];
    __shared__ __align__(16) ushort_t b_lds[64 * 32];

    const int tid = threadIdx.x;
    const int bm = blockIdx.x * 128, bn = blockIdx.y * 64;
    const int wave = tid >> 6, lane = tid & 63;
    const int quad = lane >> 4, lq = lane & 15;
    const int wr = wave >> 1, wc = wave & 1;

    f32x4 acc[4][2] = {};

    for (int k0 = 0; k0 < CC; k0 += 32) {
        stage_rows(A + (size_t)bm * CC + k0, CC, a_lds, 8192, wave, lane);
        stage_rows(Wt + (size_t)bn * CC + k0, CC, b_lds, 4096, wave, lane);
        __syncthreads();
        bf16x8 af[4], bfr[2];
#pragma unroll
        for (int mi = 0; mi < 4; ++mi)
            af[mi] = *(bf16x8*)&a_lds[(wr * 64 + mi * 16 + lq) * 32 + quad * 8];
#pragma unroll
        for (int ni = 0; ni < 2; ++ni)
            bfr[ni] = *(bf16x8*)&b_lds[(wc * 32 + ni * 16 + lq) * 32 + quad * 8];
#pragma unroll
        for (int mi = 0; mi < 4; ++mi)
#pragma unroll
            for (int ni = 0; ni < 2; ++ni)
                acc[mi][ni] = __builtin_amdgcn_mfma_f32_16x16x32_bf16(af[mi], bfr[ni], acc[mi][ni], 0, 0, 0);
        __syncthreads();
    }

#pragma unroll
    for (int mi = 0; mi < 4; ++mi)
#pragma unroll
        for (int ni = 0; ni < 2; ++ni)
#pragma unroll
            for (int r = 0; r < 4; ++r) {
                int row = bm + wr * 64 + mi * 16 + quad * 4 + r;
                int col = bn + wc * 32 + ni * 16 + lq;
                out[(size_t)row * CC + col] = acc[mi][ni][r];
            }
}

// ---------------- Launch ----------------
extern "C" void kernel_launch(void* const* d_in, const int* in_sizes, int n_in,
                              void* d_out, int out_size, void* d_ws, size_t ws_size,
                              hipStream_t stream) {
    const float* inputs_q  = (const float*)d_in[0];
    const float* inputs_kv = (const float*)d_in[1];
    const float* Wq   = (const float*)d_in[2];
    const float* Wk   = (const float*)d_in[3];
    const float* Wv   = (const float*)d_in[4];
    const float* Wout = (const float*)d_in[5];
    const float* Wpre  = (const float*)d_in[6];
    const float* Wpost = (const float*)d_in[7];
    float* out = (float*)d_out;

    const size_t nS   = (size_t)BB * HH * LL * LL;   // E: [b][lt][k][li][12]
    const size_t nQKV = (size_t)BB * HH * LL * DD;
    const size_t nW   = (size_t)CC * CC;

    ushort_t* Eb   = (ushort_t*)d_ws;
    ushort_t* Qb   = Eb + nS;
    ushort_t* Kb   = Qb + nQKV;
    ushort_t* Vtb  = Kb + nQKV;
    ushort_t* attb = Vtb + nQKV;
    ushort_t* inq  = attb + nQKV;
    ushort_t* inkv = inq + nQKV;
    ushort_t* Wqt  = inkv + nQKV;
    ushort_t* Wkt  = Wqt + nW;
    ushort_t* Wvt  = Wkt + nW;
    ushort_t* Wot  = Wvt + nW;
    float*    Zb   = (float*)(Wot + nW);             // [b][h][l] fp32, 192KB

    dim3 blk(256);

    prep<<<dim3(5568), blk, 0, stream>>>(inputs_q, inputs_kv, Wq, Wk, Wv, Wout,
                                         inq, inkv, Wqt, Wkt, Wvt, Wot, Zb);
    proj_gemm<<<dim3(32, 6, 3), blk, 0, stream>>>(inq, inkv, Wqt, Wkt, Wvt, Qb, Kb, Vtb);
    qk_premix<<<dim3(4096), blk, 0, stream>>>(Qb, Kb, Wpre, Eb, Zb);
    pv_postmix<<<dim3(256), blk, 0, stream>>>(Eb, Vtb, Wpost, Zb, attb);
    out_gemm<<<dim3(32, 12), blk, 0, stream>>>(attb, Wot, out);
}